// Round 6
// baseline (609.957 us; speedup 1.0000x reference)
//
#include <hip/hip_runtime.h>

#define NN 50000
#define FD 128
#define NE 800000
#define NG 512
#define NC 16
#define NL 3
#define NTOT 100000
#define NBLK 391            // ceil(100000/256) and ceil(50000/128)
#define NBUCK 196           // ceil(100000/512) slot-buckets
#define CAP 10240           // per-bucket capacity (avg 8163, sigma ~90)
#define BINTILE 2048
#define NBINBLK 782         // ceil(1600000/2048)
#define BNEPS 1e-5f
#define LOGITS_N (NL*NG*NC)

typedef unsigned short u16;
typedef unsigned char u8;
typedef __attribute__((ext_vector_type(8))) short short8;
typedef __attribute__((ext_vector_type(4))) float f32x4;

// ---- workspace layout (bytes), offsets 512-aligned ----
#define OFF_GCNT     0ul          // 2*512 int
#define OFF_BCUR     4096ul       // 196 int (per-bucket fill count)
#define OFF_ACC      5120ul       // 512 f32 (BN stat accumulators: S[256],Q[256])
#define MEMSET_BYTES 7168ul       // covers GCNT + BCUR + ACC
#define OFF_ROWRANGE 7680ul       // 100000 int2
#define OFF_INVCNT   808448ul     // 512 f32
#define OFF_BNSC     810496ul     // 256 f32
#define OFF_BNSH     811520ul     // 256 f32
#define OFF_WB       812544ul     // 6*128*256 bf16
#define OFF_CSR      1205760ul    // 196*10240 int (binned, then CSR in place)
#define OFF_AGGI     9233920ul    // 50000*128 bf16 (in-place -> new_i)
#define OFF_AGGU     22033920ul   // 50000*128 bf16 (in-place -> new_u)
#define OFF_XU       34833920ul   // 50000*128 bf16
#define OFF_XI       47633920ul   // 50000*128 bf16
#define OFF_XU0      60433920ul   // 50000*128 bf16 (initial cast)
#define OFF_XI0      73233920ul   // 50000*128 bf16

static __device__ __forceinline__ float bf2f(u16 v) {
  return __uint_as_float(((unsigned)v) << 16);
}
static __device__ __forceinline__ u16 f2bf(float f) {
  unsigned u = __float_as_uint(f);
  return (u16)((u + 0x7FFFu + ((u >> 16) & 1u)) >> 16);
}
// accumulate 8 packed bf16 (int4) into float[8]
static __device__ __forceinline__ void acc8(float* a, int4 v) {
  a[0] += __uint_as_float(((unsigned)v.x) << 16);
  a[1] += __uint_as_float(((unsigned)v.x) & 0xffff0000u);
  a[2] += __uint_as_float(((unsigned)v.y) << 16);
  a[3] += __uint_as_float(((unsigned)v.y) & 0xffff0000u);
  a[4] += __uint_as_float(((unsigned)v.z) << 16);
  a[5] += __uint_as_float(((unsigned)v.z) & 0xffff0000u);
  a[6] += __uint_as_float(((unsigned)v.w) << 16);
  a[7] += __uint_as_float(((unsigned)v.w) & 0xffff0000u);
}

__global__ __launch_bounds__(256) void k_hist_batch(const int* __restrict__ bu,
                                                    const int* __restrict__ bi,
                                                    int* __restrict__ gcnt) {
  int i = blockIdx.x*256 + threadIdx.x;
  if (i >= NTOT) return;
  int type = i >= NN;
  int g = type ? bi[i-NN] : bu[i];
  atomicAdd(&gcnt[type*NG + g], 1);
}

__global__ __launch_bounds__(512) void k_invcnt(const int* __restrict__ gcnt,
                                                float* __restrict__ invcnt) {
  int t = threadIdx.x;
  int c = gcnt[t] + gcnt[NG + t];
  invcnt[t] = 1.0f / (float)(c > 0 ? c : 1);
}

// bucket edges by dst-slot>>9 into fixed-capacity regions. Entry packed to 4B:
// (lslot:9 | src:17). Coalesced run writes via LDS reorder. 2048-edge tiles.
__global__ __launch_bounds__(256) void k_bin(const int* __restrict__ eu2i,
                                             const int* __restrict__ ei2u,
                                             int* __restrict__ bcursor,
                                             int* __restrict__ binned) {
  __shared__ int hist[256];
  __shared__ int scan[256];
  __shared__ int gbase[256];
  __shared__ int rbuf[BINTILE];
  __shared__ u8 rbk[BINTILE];
  int tid = threadIdx.x;
  int base = blockIdx.x * BINTILE;
  hist[tid] = 0;
  __syncthreads();
  int packr[8], bkr[8], rankr[8];
  #pragma unroll
  for (int c = 0; c < 8; c++) {
    int idx = base + c*256 + tid;
    if (idx < 2*NE) {
      int rel = idx >= NE;
      int e = rel ? idx - NE : idx;
      const int* edge = rel ? ei2u : eu2i;
      int s = edge[e];
      int d = edge[NE + e];
      int slot = d + (rel ? NN : 0);
      int bk = slot >> 9;
      bkr[c] = bk;
      packr[c] = ((slot & 511) << 17) | s;
      rankr[c] = atomicAdd(&hist[bk], 1);
    } else bkr[c] = -1;
  }
  __syncthreads();
  scan[tid] = hist[tid];
  __syncthreads();
  for (int o = 1; o < 256; o <<= 1) {
    int v = (tid >= o) ? scan[tid - o] : 0;
    __syncthreads();
    scan[tid] += v;
    __syncthreads();
  }
  if (tid < NBUCK && hist[tid] > 0)
    gbase[tid] = atomicAdd(&bcursor[tid], hist[tid]);
  __syncthreads();
  #pragma unroll
  for (int c = 0; c < 8; c++) {
    if (bkr[c] >= 0) {
      int bk = bkr[c];
      int lpos = scan[bk] - hist[bk] + rankr[c];
      rbuf[lpos] = packr[c];
      rbk[lpos] = (u8)bk;
    }
  }
  __syncthreads();
  int nv = min(BINTILE, 2*NE - base);
  for (int j = tid; j < nv; j += 256) {
    int bk = rbk[j];
    int outpos = bk*CAP + gbase[bk] + (j - (scan[bk] - hist[bk]));
    binned[outpos] = rbuf[j];
  }
}

// one block per bucket: local hist+scan -> rowrange, LDS-staged scatter,
// CSR written IN PLACE over the binned region (block-private).
__global__ __launch_bounds__(256) void k_csrbuild(const int* __restrict__ bcursor,
                                                  int* __restrict__ csrbin,
                                                  int2* __restrict__ rowrange) {
  __shared__ int lcnt[512];
  __shared__ int scan2[256];
  __shared__ int lcsr[CAP];
  int b = blockIdx.x;
  int tid = threadIdx.x;
  int slot0 = b << 9;
  int nslots = min(512, NTOT - slot0);
  int n = bcursor[b];
  int gb = b * CAP;
  lcnt[tid] = 0; lcnt[tid + 256] = 0;
  __syncthreads();
  for (int i = tid; i < n; i += 256) {
    int e = csrbin[gb + i];
    atomicAdd(&lcnt[e >> 17], 1);
  }
  __syncthreads();
  int v0 = lcnt[2*tid], v1 = lcnt[2*tid + 1];
  int ps = v0 + v1;
  scan2[tid] = ps;
  __syncthreads();
  for (int o = 1; o < 256; o <<= 1) {
    int v = (tid >= o) ? scan2[tid - o] : 0;
    __syncthreads();
    scan2[tid] += v;
    __syncthreads();
  }
  int e0 = scan2[tid] - ps;       // exclusive prefix for slot 2*tid
  int e1 = e0 + v0;
  if (2*tid < nslots)     rowrange[slot0 + 2*tid]     = make_int2(gb + e0, gb + e0 + v0);
  if (2*tid + 1 < nslots) rowrange[slot0 + 2*tid + 1] = make_int2(gb + e1, gb + e1 + v1);
  __syncthreads();
  lcnt[2*tid] = e0; lcnt[2*tid + 1] = e1;   // cursors
  __syncthreads();
  for (int i = tid; i < n; i += 256) {
    int e = csrbin[gb + i];
    int pos = atomicAdd(&lcnt[e >> 17], 1);
    lcsr[pos] = e & 0x1FFFF;
  }
  __syncthreads();
  for (int i = tid; i < n; i += 256) csrbin[gb + i] = lcsr[i];
}

// fp32 -> bf16 cast of initial features
__global__ __launch_bounds__(256) void k_castX(const float* __restrict__ xu,
                                               const float* __restrict__ xi,
                                               u16* __restrict__ xbu,
                                               u16* __restrict__ xbi) {
  int b = blockIdx.x;
  int half = b >= 6250;
  const float* src = half ? xi : xu;
  u16* dst = half ? xbi : xbu;
  int i = ((half ? b - 6250 : b)*256 + threadIdx.x) * 4;
  float4 v = *(const float4*)(src + i);
  ushort4 o = { f2bf(v.x), f2bf(v.y), f2bf(v.z), f2bf(v.w) };
  *(ushort4*)(dst + i) = o;
}

// WB[lr][h][k]: k<128 -> Wrel[l][h][k], else Wroot[l][h][k-128]   (bf16)
__global__ __launch_bounds__(256) void k_castW(const float* __restrict__ WrelA,
                                               const float* __restrict__ WrootA,
                                               const float* __restrict__ WrelB,
                                               const float* __restrict__ WrootB,
                                               u16* __restrict__ WB) {
  int idx = blockIdx.x*256 + threadIdx.x;   // < 6*32768
  int lr = idx >> 15;
  int rem = idx & 32767;
  int h = rem >> 8;
  int k = rem & 255;
  int l = lr >> 1;
  int rel = lr & 1;
  const float* Wr = rel ? WrelB : WrelA;
  const float* Wo = rel ? WrootB : WrootA;
  float v = (k < FD) ? Wr[(l*FD + h)*FD + k] : Wo[(l*FD + h)*FD + (k-FD)];
  WB[idx] = f2bf(v);
}

// one wave per dst row; 16B/lane loads (16 lanes = one 256B row), quarter-waves
// take different edges. Depth-2 software pipeline: next iteration's two row
// loads are issued before consuming the current pair (4 row loads in flight).
// blocks [0,12500): u2i (curU -> aggI), [12500,25000): i2u (curI -> aggU)
__global__ __launch_bounds__(256) void k_gather(const u16* __restrict__ curU,
                                                const u16* __restrict__ curI,
                                                const int2* __restrict__ rowrange,
                                                const int* __restrict__ csr,
                                                u16* __restrict__ aggI,
                                                u16* __restrict__ aggU) {
  int b = blockIdx.x;
  int half = b >= 12500;
  int blk = half ? b - 12500 : b;
  const u16* src = half ? curI : curU;
  u16* out = half ? aggU : aggI;
  int slotbase = half ? NN : 0;
  int wid = __builtin_amdgcn_readfirstlane(threadIdx.x >> 6);
  int row = blk*4 + wid;
  int lane = threadIdx.x & 63;
  int q = lane >> 4;
  int c16 = (lane & 15) * 8;      // 8 bf16 = 16B per lane
  const u16* sp = src + c16;
  int2 pr = rowrange[slotbase + row];
  int p = pr.x, pe = pr.y;
  float a0[8], a1[8];
  #pragma unroll
  for (int j = 0; j < 8; j++) { a0[j] = 0.f; a1[j] = 0.f; }
  if (p + 8 <= pe) {
    int i0 = csr[p + q], i1 = csr[p + 4 + q];
    int4 u0 = *(const int4*)(sp + (size_t)i0*FD);
    int4 u1 = *(const int4*)(sp + (size_t)i1*FD);
    p += 8;
    while (p + 8 <= pe) {
      int j0 = csr[p + q], j1 = csr[p + 4 + q];
      int4 w0 = *(const int4*)(sp + (size_t)j0*FD);
      int4 w1 = *(const int4*)(sp + (size_t)j1*FD);
      acc8(a0, u0); acc8(a1, u1);
      u0 = w0; u1 = w1;
      p += 8;
    }
    acc8(a0, u0); acc8(a1, u1);
  }
  int rem = pe - p;               // 0..7
  if (q < rem) {
    int s = csr[p + q];
    acc8(a0, *(const int4*)(sp + (size_t)s*FD));
  }
  if (q + 4 < rem) {
    int s = csr[p + 4 + q];
    acc8(a1, *(const int4*)(sp + (size_t)s*FD));
  }
  #pragma unroll
  for (int j = 0; j < 8; j++) a0[j] += a1[j];
  #pragma unroll
  for (int j = 0; j < 8; j++) {
    a0[j] += __shfl_xor(a0[j], 16);
    a0[j] += __shfl_xor(a0[j], 32);
  }
  if (q == 0) {
    int4 o;
    o.x = (unsigned)f2bf(a0[0]) | ((unsigned)f2bf(a0[1]) << 16);
    o.y = (unsigned)f2bf(a0[2]) | ((unsigned)f2bf(a0[3]) << 16);
    o.z = (unsigned)f2bf(a0[4]) | ((unsigned)f2bf(a0[5]) << 16);
    o.w = (unsigned)f2bf(a0[6]) | ((unsigned)f2bf(a0[7]) << 16);
    *(int4*)(out + (size_t)row*FD + c16) = o;
  }
}

// MFMA bf16 GEMM: new[n,h] = [agg|cur][n,0:256] @ WB[h,0:256]^T + bias[h]
// 128x128 tile, BK=64, LDS row stride 72 bf16. BN relu-stats -> global atomics.
__global__ __launch_bounds__(256) void k_gemm(u16* __restrict__ aggU,
                                              u16* __restrict__ aggI,
                                              const u16* __restrict__ curU,
                                              const u16* __restrict__ curI,
                                              const u16* __restrict__ WBl,
                                              const float* __restrict__ bI2U,
                                              const float* __restrict__ bU2I,
                                              float* __restrict__ accSQ) {
  __shared__ u16 As[128*72];
  __shared__ u16 Bs[128*72];
  __shared__ float Sred[2][4][128];
  int ty = blockIdx.y;
  u16* A1 = ty ? aggI : aggU;
  const u16* A2 = ty ? curI : curU;
  const u16* WBp = ty ? WBl : (WBl + 32768);
  const float* bias = ty ? bU2I : bI2U;
  int tid = threadIdx.x;
  int n0 = blockIdx.x * 128;
  int w = __builtin_amdgcn_readfirstlane(tid >> 6);
  int lane = tid & 63;
  int l15 = lane & 15;
  int quad = lane >> 4;
  f32x4 acc[2][8];
  #pragma unroll
  for (int tr = 0; tr < 2; tr++)
    #pragma unroll
    for (int tc = 0; tc < 8; tc++)
      acc[tr][tc] = (f32x4){0.f,0.f,0.f,0.f};

  for (int ch = 0; ch < 4; ch++) {
    const u16* Ap = (ch < 2) ? ((const u16*)A1 + ch*64) : (A2 + (ch-2)*64);
    #pragma unroll
    for (int i = 0; i < 4; i++) {
      int e = i*256 + tid;
      int r = e >> 3, seg = e & 7;
      int4 v = {0,0,0,0};
      int gr = n0 + r;
      if (gr < NN) v = *(const int4*)(Ap + (size_t)gr*FD + seg*8);
      *(int4*)&As[r*72 + seg*8] = v;
    }
    #pragma unroll
    for (int i = 0; i < 4; i++) {
      int e = i*256 + tid;
      int r = e >> 3, seg = e & 7;
      int4 v = *(const int4*)(WBp + r*256 + ch*64 + seg*8);
      *(int4*)&Bs[r*72 + seg*8] = v;
    }
    __syncthreads();
    #pragma unroll
    for (int ks = 0; ks < 2; ks++) {
      int kb = ks*32 + quad*8;
      short8 af0 = *(const short8*)&As[(w*32 + l15)*72 + kb];
      short8 af1 = *(const short8*)&As[(w*32 + 16 + l15)*72 + kb];
      short8 bf[8];
      #pragma unroll
      for (int tc = 0; tc < 8; tc++)
        bf[tc] = *(const short8*)&Bs[(tc*16 + l15)*72 + kb];
      #pragma unroll
      for (int tc = 0; tc < 8; tc++) {
        acc[0][tc] = __builtin_amdgcn_mfma_f32_16x16x32_bf16(af0, bf[tc], acc[0][tc], 0, 0, 0);
        acc[1][tc] = __builtin_amdgcn_mfma_f32_16x16x32_bf16(af1, bf[tc], acc[1][tc], 0, 0, 0);
      }
    }
    __syncthreads();
  }
  float sv[8], qv[8], bj[8];
  #pragma unroll
  for (int tc = 0; tc < 8; tc++) {
    bj[tc] = bias[tc*16 + l15];
    sv[tc] = 0.f; qv[tc] = 0.f;
  }
  #pragma unroll
  for (int tr = 0; tr < 2; tr++) {
    int rbase = n0 + w*32 + tr*16 + quad*4;
    #pragma unroll
    for (int tc = 0; tc < 8; tc++) {
      int col = tc*16 + l15;
      #pragma unroll
      for (int g = 0; g < 4; g++) {
        int r = rbase + g;
        if (r < NN) {
          float v = acc[tr][tc][g] + bj[tc];
          float y = v > 0.f ? v : 0.f;
          sv[tc] += y; qv[tc] += y*y;
          A1[(size_t)r*FD + col] = f2bf(v);
        }
      }
    }
  }
  #pragma unroll
  for (int tc = 0; tc < 8; tc++) {
    sv[tc] += __shfl_xor(sv[tc], 16); qv[tc] += __shfl_xor(qv[tc], 16);
    sv[tc] += __shfl_xor(sv[tc], 32); qv[tc] += __shfl_xor(qv[tc], 32);
  }
  if (quad == 0) {
    #pragma unroll
    for (int tc = 0; tc < 8; tc++) {
      Sred[0][w][tc*16 + l15] = sv[tc];
      Sred[1][w][tc*16 + l15] = qv[tc];
    }
  }
  __syncthreads();
  if (tid < 128) {
    float s = Sred[0][0][tid] + Sred[0][1][tid] + Sred[0][2][tid] + Sred[0][3][tid];
    float q = Sred[1][0][tid] + Sred[1][1][tid] + Sred[1][2][tid] + Sred[1][3][tid];
    atomicAdd(&accSQ[ty*128 + tid], s);
    atomicAdd(&accSQ[256 + ty*128 + tid], q);
  }
}

// tiny: fold accumulated stats -> scale/shift; re-zero accumulators for next layer
__global__ __launch_bounds__(256) void k_bnfinal(float* __restrict__ accSQ,
                                                 const float* __restrict__ gu,
                                                 const float* __restrict__ bu,
                                                 const float* __restrict__ gi,
                                                 const float* __restrict__ bi,
                                                 float* __restrict__ bnsc,
                                                 float* __restrict__ bnsh) {
  int tid = threadIdx.x;
  int type = tid >> 7;            // 0=user, 1=item
  int c = tid & 127;
  float s = accSQ[tid];
  float q = accSQ[256 + tid];
  accSQ[tid] = 0.f;
  accSQ[256 + tid] = 0.f;
  float inv = 1.0f / (float)NN;
  float mean = s * inv;
  float var = q * inv - mean*mean;
  float rstd = rsqrtf(var + BNEPS);
  float g = type ? gi[c] : gu[c];
  float bb = type ? bi[c] : bu[c];
  float sc = rstd * g;
  bnsc[tid] = sc;
  bnsh[tid] = bb - mean * sc;
}

// BN-apply + fused mean-pool (batch ids sorted -> per-run register accumulation)
__global__ __launch_bounds__(256) void k_bnapply(const u16* __restrict__ newU,
                                                 const u16* __restrict__ newI,
                                                 const int* __restrict__ bu,
                                                 const int* __restrict__ bi,
                                                 const float* __restrict__ bnsc,
                                                 const float* __restrict__ bnsh,
                                                 const float* __restrict__ invcnt,
                                                 u16* __restrict__ xu,
                                                 u16* __restrict__ xi,
                                                 float* __restrict__ feats) {
  int type = blockIdx.y;          // 0=user, 1=item
  const u16* in = type ? newI : newU;
  const int* bt = type ? bi : bu;
  u16* out = type ? xi : xu;
  int tid = threadIdx.x;
  int c = tid & 127;
  int rh = tid >> 7;
  float sc = bnsc[type*128 + c];
  float sh = bnsh[type*128 + c];
  int rs = blockIdx.x*128 + rh*64;
  int re = rs + 64; if (re > NN) re = NN;
  if (rs >= re) return;
  int gcur = bt[rs];
  float acc = 0.f;
  for (int r = rs; r < re; r++) {
    int g = bt[r];
    if (g != gcur) {
      atomicAdd(&feats[(size_t)gcur*FD + c], acc * invcnt[gcur]);
      acc = 0.f; gcur = g;
    }
    float y = bf2f(in[(size_t)r*FD + c]);
    y = y > 0.f ? y : 0.f;
    float o = y * sc + sh;
    out[(size_t)r*FD + c] = f2bf(o);
    acc += o;
  }
  atomicAdd(&feats[(size_t)gcur*FD + c], acc * invcnt[gcur]);
}

__global__ __launch_bounds__(256) void k_heads(const float* __restrict__ feats,
                                               const float* __restrict__ fcW,
                                               const float* __restrict__ fcb,
                                               float* __restrict__ logits) {
  int idx = blockIdx.x*256 + threadIdx.x;
  if (idx >= LOGITS_N) return;
  int l = idx >> 13;
  int rem = idx & 8191;
  int g = rem >> 4;
  int c = rem & 15;
  const float* f = feats + ((size_t)l*NG + g)*FD;
  const float* w = fcW + ((size_t)l*NC + c)*FD;
  float s = 0.f;
  #pragma unroll
  for (int k = 0; k < FD; k += 4) {
    float4 fv = *(const float4*)(f + k);
    float4 wv = *(const float4*)(w + k);
    s += fv.x*wv.x + fv.y*wv.y + fv.z*wv.z + fv.w*wv.w;
  }
  logits[idx] = s + fcb[l*NC + c];
}

extern "C" void kernel_launch(void* const* d_in, const int* in_sizes, int n_in,
                              void* d_out, int out_size, void* d_ws, size_t ws_size,
                              hipStream_t stream) {
  const float* x_user   = (const float*)d_in[0];
  const float* x_item   = (const float*)d_in[1];
  const int*   eu2i     = (const int*)d_in[2];
  const int*   ei2u     = (const int*)d_in[3];
  const int*   bu       = (const int*)d_in[4];
  const int*   bi       = (const int*)d_in[5];
  const float* Wrel_u2i = (const float*)d_in[6];
  const float* Wroot_u2i= (const float*)d_in[7];
  const float* b_u2i    = (const float*)d_in[8];
  const float* Wrel_i2u = (const float*)d_in[9];
  const float* Wroot_i2u= (const float*)d_in[10];
  const float* b_i2u    = (const float*)d_in[11];
  const float* bn_g_user= (const float*)d_in[12];
  const float* bn_b_user= (const float*)d_in[13];
  const float* bn_g_item= (const float*)d_in[14];
  const float* bn_b_item= (const float*)d_in[15];
  const float* fcW      = (const float*)d_in[16];
  const float* fcb      = (const float*)d_in[17];

  char* ws = (char*)d_ws;
  int*   gcnt   = (int*)(ws + OFF_GCNT);
  int*   bcursor= (int*)(ws + OFF_BCUR);
  float* accSQ  = (float*)(ws + OFF_ACC);
  int2*  rowrange = (int2*)(ws + OFF_ROWRANGE);
  float* invcnt = (float*)(ws + OFF_INVCNT);
  float* bnsc   = (float*)(ws + OFF_BNSC);
  float* bnsh   = (float*)(ws + OFF_BNSH);
  u16*   WB     = (u16*)(ws + OFF_WB);
  int*   csrbin = (int*)(ws + OFF_CSR);
  u16*   aggI   = (u16*)(ws + OFF_AGGI);
  u16*   aggU   = (u16*)(ws + OFF_AGGU);
  u16*   xu     = (u16*)(ws + OFF_XU);
  u16*   xi     = (u16*)(ws + OFF_XI);
  u16*   xu0    = (u16*)(ws + OFF_XU0);
  u16*   xi0    = (u16*)(ws + OFF_XI0);
  float* fout   = (float*)d_out;
  float* featsAll = fout + LOGITS_N;

  hipMemsetAsync(ws, 0, MEMSET_BYTES, stream);
  hipMemsetAsync(featsAll, 0, (size_t)NL*NG*FD*sizeof(float), stream);
  k_hist_batch<<<NBLK, 256, 0, stream>>>(bu, bi, gcnt);
  k_bin<<<NBINBLK, 256, 0, stream>>>(eu2i, ei2u, bcursor, csrbin);
  k_invcnt<<<1, 512, 0, stream>>>(gcnt, invcnt);
  k_csrbuild<<<NBUCK, 256, 0, stream>>>(bcursor, csrbin, rowrange);
  k_castX<<<12500, 256, 0, stream>>>(x_user, x_item, xu0, xi0);
  k_castW<<<768, 256, 0, stream>>>(Wrel_u2i, Wroot_u2i, Wrel_i2u, Wroot_i2u, WB);

  const u16* curU = xu0;
  const u16* curI = xi0;
  for (int l = 0; l < NL; l++) {
    k_gather<<<25000, 256, 0, stream>>>(curU, curI, rowrange, csrbin, aggI, aggU);
    k_gemm<<<dim3(NBLK,2), 256, 0, stream>>>(aggU, aggI, curU, curI,
                                             WB + (size_t)l*2*32768,
                                             b_i2u + l*FD, b_u2i + l*FD,
                                             accSQ);
    k_bnfinal<<<1, 256, 0, stream>>>(accSQ, bn_g_user, bn_b_user,
                                     bn_g_item, bn_b_item, bnsc, bnsh);
    k_bnapply<<<dim3(NBLK,2), 256, 0, stream>>>(aggU, aggI, bu, bi, bnsc, bnsh,
                                                invcnt, xu, xi,
                                                featsAll + (size_t)l*NG*FD);
    curU = xu; curI = xi;
  }
  k_heads<<<96, 256, 0, stream>>>(featsAll, fcW, fcb, fout);
}

// Round 7
// 515.678 us; speedup vs baseline: 1.1828x; 1.1828x over previous
//
#include <hip/hip_runtime.h>

#define NN 50000
#define FD 128
#define NE 800000
#define NG 512
#define NC 16
#define NL 3
#define NTOT 100000
#define NBLK 391            // ceil(100000/256) and ceil(50000/128)
#define NBUCK 196           // ceil(100000/512) slot-buckets
#define CAP 10240           // per-bucket capacity (avg 8163, sigma ~90)
#define BINTILE 2048
#define NBINBLK 782         // ceil(1600000/2048)
#define BNEPS 1e-5f
#define LOGITS_N (NL*NG*NC)

typedef unsigned short u16;
typedef unsigned char u8;
typedef __attribute__((ext_vector_type(8))) short short8;
typedef __attribute__((ext_vector_type(4))) float f32x4;

// ---- workspace layout (bytes), offsets 512-aligned ----
#define OFF_GCNT     0ul          // 2*512 int
#define OFF_BCUR     4096ul       // 196 int (per-bucket fill count)
#define OFF_ACC      5120ul       // 512 f32 (BN stat accumulators: S[256],Q[256])
#define MEMSET_BYTES 7168ul       // covers GCNT + BCUR + ACC
#define OFF_USTART   7680ul       // 513 int
#define OFF_ISTART   10240ul      // 513 int
#define OFF_INVCNT   12800ul      // 512 f32
#define OFF_BNSC     14848ul      // 256 f32
#define OFF_BNSH     15872ul      // 256 f32
#define OFF_ROWRANGE 16896ul      // 100000 int2
#define OFF_WB       817152ul     // 6*128*256 bf16
#define OFF_CSR      1210368ul    // 196*10240 int (binned, then CSR in place)
#define OFF_AGGI     9238528ul    // 50000*128 bf16 (in-place -> new_i)
#define OFF_AGGU     22038528ul   // 50000*128 bf16 (in-place -> new_u)
#define OFF_XU       34838528ul   // 50000*128 bf16
#define OFF_XI       47638528ul   // 50000*128 bf16
#define OFF_XU0      60438528ul   // 50000*128 bf16 (initial cast)
#define OFF_XI0      73238528ul   // 50000*128 bf16

static __device__ __forceinline__ float bf2f(u16 v) {
  return __uint_as_float(((unsigned)v) << 16);
}
static __device__ __forceinline__ u16 f2bf(float f) {
  unsigned u = __float_as_uint(f);
  return (u16)((u + 0x7FFFu + ((u >> 16) & 1u)) >> 16);
}
// accumulate 8 packed bf16 (int4) into float[8]
static __device__ __forceinline__ void acc8(float* a, int4 v) {
  a[0] += __uint_as_float(((unsigned)v.x) << 16);
  a[1] += __uint_as_float(((unsigned)v.x) & 0xffff0000u);
  a[2] += __uint_as_float(((unsigned)v.y) << 16);
  a[3] += __uint_as_float(((unsigned)v.y) & 0xffff0000u);
  a[4] += __uint_as_float(((unsigned)v.z) << 16);
  a[5] += __uint_as_float(((unsigned)v.z) & 0xffff0000u);
  a[6] += __uint_as_float(((unsigned)v.w) << 16);
  a[7] += __uint_as_float(((unsigned)v.w) & 0xffff0000u);
}
// unpack 8 bf16 (int4) into float[8]
static __device__ __forceinline__ void unp8(float* a, int4 v) {
  a[0] = __uint_as_float(((unsigned)v.x) << 16);
  a[1] = __uint_as_float(((unsigned)v.x) & 0xffff0000u);
  a[2] = __uint_as_float(((unsigned)v.y) << 16);
  a[3] = __uint_as_float(((unsigned)v.y) & 0xffff0000u);
  a[4] = __uint_as_float(((unsigned)v.z) << 16);
  a[5] = __uint_as_float(((unsigned)v.z) & 0xffff0000u);
  a[6] = __uint_as_float(((unsigned)v.w) << 16);
  a[7] = __uint_as_float(((unsigned)v.w) & 0xffff0000u);
}

__global__ __launch_bounds__(256) void k_hist_batch(const int* __restrict__ bu,
                                                    const int* __restrict__ bi,
                                                    int* __restrict__ gcnt) {
  int i = blockIdx.x*256 + threadIdx.x;
  if (i >= NTOT) return;
  int type = i >= NN;
  int g = type ? bi[i-NN] : bu[i];
  atomicAdd(&gcnt[type*NG + g], 1);
}

// scan per-type graph counts -> contiguous row ranges (batch ids are sorted)
__global__ __launch_bounds__(512) void k_scan_g(const int* __restrict__ gcnt,
                                                int* __restrict__ ustart,
                                                int* __restrict__ istart,
                                                float* __restrict__ invcnt) {
  __shared__ int pu[512], pi[512];
  int t = threadIdx.x;
  int cu = gcnt[t], ci = gcnt[NG + t];
  pu[t] = cu; pi[t] = ci;
  __syncthreads();
  for (int off = 1; off < 512; off <<= 1) {
    int vu = (t >= off) ? pu[t-off] : 0;
    int vi = (t >= off) ? pi[t-off] : 0;
    __syncthreads();
    pu[t] += vu; pi[t] += vi;
    __syncthreads();
  }
  ustart[t] = pu[t] - cu;
  istart[t] = pi[t] - ci;
  if (t == 511) { ustart[NG] = pu[511]; istart[NG] = pi[511]; }
  int c = cu + ci;
  invcnt[t] = 1.0f / (float)(c > 0 ? c : 1);
}

// bucket edges by dst-slot>>9 into fixed-capacity regions. Entry packed to 4B:
// (lslot:9 | src:17). Coalesced run writes via LDS reorder. 2048-edge tiles.
__global__ __launch_bounds__(256) void k_bin(const int* __restrict__ eu2i,
                                             const int* __restrict__ ei2u,
                                             int* __restrict__ bcursor,
                                             int* __restrict__ binned) {
  __shared__ int hist[256];
  __shared__ int scan[256];
  __shared__ int gbase[256];
  __shared__ int rbuf[BINTILE];
  __shared__ u8 rbk[BINTILE];
  int tid = threadIdx.x;
  int base = blockIdx.x * BINTILE;
  hist[tid] = 0;
  __syncthreads();
  int packr[8], bkr[8], rankr[8];
  #pragma unroll
  for (int c = 0; c < 8; c++) {
    int idx = base + c*256 + tid;
    if (idx < 2*NE) {
      int rel = idx >= NE;
      int e = rel ? idx - NE : idx;
      const int* edge = rel ? ei2u : eu2i;
      int s = edge[e];
      int d = edge[NE + e];
      int slot = d + (rel ? NN : 0);
      int bk = slot >> 9;
      bkr[c] = bk;
      packr[c] = ((slot & 511) << 17) | s;
      rankr[c] = atomicAdd(&hist[bk], 1);
    } else bkr[c] = -1;
  }
  __syncthreads();
  scan[tid] = hist[tid];
  __syncthreads();
  for (int o = 1; o < 256; o <<= 1) {
    int v = (tid >= o) ? scan[tid - o] : 0;
    __syncthreads();
    scan[tid] += v;
    __syncthreads();
  }
  if (tid < NBUCK && hist[tid] > 0)
    gbase[tid] = atomicAdd(&bcursor[tid], hist[tid]);
  __syncthreads();
  #pragma unroll
  for (int c = 0; c < 8; c++) {
    if (bkr[c] >= 0) {
      int bk = bkr[c];
      int lpos = scan[bk] - hist[bk] + rankr[c];
      rbuf[lpos] = packr[c];
      rbk[lpos] = (u8)bk;
    }
  }
  __syncthreads();
  int nv = min(BINTILE, 2*NE - base);
  for (int j = tid; j < nv; j += 256) {
    int bk = rbk[j];
    int outpos = bk*CAP + gbase[bk] + (j - (scan[bk] - hist[bk]));
    binned[outpos] = rbuf[j];
  }
}

// one block per bucket: local hist+scan -> rowrange, LDS-staged scatter,
// CSR written IN PLACE over the binned region (block-private).
__global__ __launch_bounds__(256) void k_csrbuild(const int* __restrict__ bcursor,
                                                  int* __restrict__ csrbin,
                                                  int2* __restrict__ rowrange) {
  __shared__ int lcnt[512];
  __shared__ int scan2[256];
  __shared__ int lcsr[CAP];
  int b = blockIdx.x;
  int tid = threadIdx.x;
  int slot0 = b << 9;
  int nslots = min(512, NTOT - slot0);
  int n = bcursor[b];
  int gb = b * CAP;
  lcnt[tid] = 0; lcnt[tid + 256] = 0;
  __syncthreads();
  for (int i = tid; i < n; i += 256) {
    int e = csrbin[gb + i];
    atomicAdd(&lcnt[e >> 17], 1);
  }
  __syncthreads();
  int v0 = lcnt[2*tid], v1 = lcnt[2*tid + 1];
  int ps = v0 + v1;
  scan2[tid] = ps;
  __syncthreads();
  for (int o = 1; o < 256; o <<= 1) {
    int v = (tid >= o) ? scan2[tid - o] : 0;
    __syncthreads();
    scan2[tid] += v;
    __syncthreads();
  }
  int e0 = scan2[tid] - ps;       // exclusive prefix for slot 2*tid
  int e1 = e0 + v0;
  if (2*tid < nslots)     rowrange[slot0 + 2*tid]     = make_int2(gb + e0, gb + e0 + v0);
  if (2*tid + 1 < nslots) rowrange[slot0 + 2*tid + 1] = make_int2(gb + e1, gb + e1 + v1);
  __syncthreads();
  lcnt[2*tid] = e0; lcnt[2*tid + 1] = e1;   // cursors
  __syncthreads();
  for (int i = tid; i < n; i += 256) {
    int e = csrbin[gb + i];
    int pos = atomicAdd(&lcnt[e >> 17], 1);
    lcsr[pos] = e & 0x1FFFF;
  }
  __syncthreads();
  for (int i = tid; i < n; i += 256) csrbin[gb + i] = lcsr[i];
}

// fp32 -> bf16 cast of initial features
__global__ __launch_bounds__(256) void k_castX(const float* __restrict__ xu,
                                               const float* __restrict__ xi,
                                               u16* __restrict__ xbu,
                                               u16* __restrict__ xbi) {
  int b = blockIdx.x;
  int half = b >= 6250;
  const float* src = half ? xi : xu;
  u16* dst = half ? xbi : xbu;
  int i = ((half ? b - 6250 : b)*256 + threadIdx.x) * 4;
  float4 v = *(const float4*)(src + i);
  ushort4 o = { f2bf(v.x), f2bf(v.y), f2bf(v.z), f2bf(v.w) };
  *(ushort4*)(dst + i) = o;
}

// WB[lr][h][k]: k<128 -> Wrel[l][h][k], else Wroot[l][h][k-128]   (bf16)
__global__ __launch_bounds__(256) void k_castW(const float* __restrict__ WrelA,
                                               const float* __restrict__ WrootA,
                                               const float* __restrict__ WrelB,
                                               const float* __restrict__ WrootB,
                                               u16* __restrict__ WB) {
  int idx = blockIdx.x*256 + threadIdx.x;   // < 6*32768
  int lr = idx >> 15;
  int rem = idx & 32767;
  int h = rem >> 8;
  int k = rem & 255;
  int l = lr >> 1;
  int rel = lr & 1;
  const float* Wr = rel ? WrelB : WrelA;
  const float* Wo = rel ? WrootB : WrootA;
  float v = (k < FD) ? Wr[(l*FD + h)*FD + k] : Wo[(l*FD + h)*FD + (k-FD)];
  WB[idx] = f2bf(v);
}

// one wave per dst row; 16B/lane loads (16 lanes = one 256B row), quarter-waves
// take different edges; 2 chains x 8-edge iters with index prefetch (round-5
// form: the explicit depth-2 pipeline of round-6 regressed, fabric-bound).
// blocks [0,12500): u2i (curU -> aggI), [12500,25000): i2u (curI -> aggU)
__global__ __launch_bounds__(256) void k_gather(const u16* __restrict__ curU,
                                                const u16* __restrict__ curI,
                                                const int2* __restrict__ rowrange,
                                                const int* __restrict__ csr,
                                                u16* __restrict__ aggI,
                                                u16* __restrict__ aggU) {
  int b = blockIdx.x;
  int half = b >= 12500;
  int blk = half ? b - 12500 : b;
  const u16* src = half ? curI : curU;
  u16* out = half ? aggU : aggI;
  int slotbase = half ? NN : 0;
  int wid = __builtin_amdgcn_readfirstlane(threadIdx.x >> 6);
  int row = blk*4 + wid;
  int lane = threadIdx.x & 63;
  int q = lane >> 4;
  int c16 = (lane & 15) * 8;      // 8 bf16 = 16B per lane
  const u16* sp = src + c16;
  int2 pr = rowrange[slotbase + row];
  int p = pr.x, pe = pr.y;
  float a0[8], a1[8];
  #pragma unroll
  for (int j = 0; j < 8; j++) { a0[j] = 0.f; a1[j] = 0.f; }
  if (p + 8 <= pe) {
    int i0 = csr[p + q], i1 = csr[p + 4 + q];
    while (p + 16 <= pe) {
      int n0 = csr[p + 8 + q], n1 = csr[p + 12 + q];
      int4 v0 = *(const int4*)(sp + (size_t)i0*FD);
      int4 v1 = *(const int4*)(sp + (size_t)i1*FD);
      acc8(a0, v0); acc8(a1, v1);
      i0 = n0; i1 = n1; p += 8;
    }
    int4 v0 = *(const int4*)(sp + (size_t)i0*FD);
    int4 v1 = *(const int4*)(sp + (size_t)i1*FD);
    acc8(a0, v0); acc8(a1, v1);
    p += 8;
  }
  int rem = pe - p;               // 0..7
  if (q < rem) {
    int s = csr[p + q];
    acc8(a0, *(const int4*)(sp + (size_t)s*FD));
  }
  if (q + 4 < rem) {
    int s = csr[p + 4 + q];
    acc8(a1, *(const int4*)(sp + (size_t)s*FD));
  }
  #pragma unroll
  for (int j = 0; j < 8; j++) a0[j] += a1[j];
  #pragma unroll
  for (int j = 0; j < 8; j++) {
    a0[j] += __shfl_xor(a0[j], 16);
    a0[j] += __shfl_xor(a0[j], 32);
  }
  if (q == 0) {
    int4 o;
    o.x = (unsigned)f2bf(a0[0]) | ((unsigned)f2bf(a0[1]) << 16);
    o.y = (unsigned)f2bf(a0[2]) | ((unsigned)f2bf(a0[3]) << 16);
    o.z = (unsigned)f2bf(a0[4]) | ((unsigned)f2bf(a0[5]) << 16);
    o.w = (unsigned)f2bf(a0[6]) | ((unsigned)f2bf(a0[7]) << 16);
    *(int4*)(out + (size_t)row*FD + c16) = o;
  }
}

// MFMA bf16 GEMM: new[n,h] = [agg|cur][n,0:256] @ WB[h,0:256]^T + bias[h]
// 128x128 tile, BK=64, LDS row stride 72 bf16. BN relu-stats -> global atomics.
__global__ __launch_bounds__(256) void k_gemm(u16* __restrict__ aggU,
                                              u16* __restrict__ aggI,
                                              const u16* __restrict__ curU,
                                              const u16* __restrict__ curI,
                                              const u16* __restrict__ WBl,
                                              const float* __restrict__ bI2U,
                                              const float* __restrict__ bU2I,
                                              float* __restrict__ accSQ) {
  __shared__ u16 As[128*72];
  __shared__ u16 Bs[128*72];
  __shared__ float Sred[2][4][128];
  int ty = blockIdx.y;
  u16* A1 = ty ? aggI : aggU;
  const u16* A2 = ty ? curI : curU;
  const u16* WBp = ty ? WBl : (WBl + 32768);
  const float* bias = ty ? bU2I : bI2U;
  int tid = threadIdx.x;
  int n0 = blockIdx.x * 128;
  int w = __builtin_amdgcn_readfirstlane(tid >> 6);
  int lane = tid & 63;
  int l15 = lane & 15;
  int quad = lane >> 4;
  f32x4 acc[2][8];
  #pragma unroll
  for (int tr = 0; tr < 2; tr++)
    #pragma unroll
    for (int tc = 0; tc < 8; tc++)
      acc[tr][tc] = (f32x4){0.f,0.f,0.f,0.f};

  for (int ch = 0; ch < 4; ch++) {
    const u16* Ap = (ch < 2) ? ((const u16*)A1 + ch*64) : (A2 + (ch-2)*64);
    #pragma unroll
    for (int i = 0; i < 4; i++) {
      int e = i*256 + tid;
      int r = e >> 3, seg = e & 7;
      int4 v = {0,0,0,0};
      int gr = n0 + r;
      if (gr < NN) v = *(const int4*)(Ap + (size_t)gr*FD + seg*8);
      *(int4*)&As[r*72 + seg*8] = v;
    }
    #pragma unroll
    for (int i = 0; i < 4; i++) {
      int e = i*256 + tid;
      int r = e >> 3, seg = e & 7;
      int4 v = *(const int4*)(WBp + r*256 + ch*64 + seg*8);
      *(int4*)&Bs[r*72 + seg*8] = v;
    }
    __syncthreads();
    #pragma unroll
    for (int ks = 0; ks < 2; ks++) {
      int kb = ks*32 + quad*8;
      short8 af0 = *(const short8*)&As[(w*32 + l15)*72 + kb];
      short8 af1 = *(const short8*)&As[(w*32 + 16 + l15)*72 + kb];
      short8 bf[8];
      #pragma unroll
      for (int tc = 0; tc < 8; tc++)
        bf[tc] = *(const short8*)&Bs[(tc*16 + l15)*72 + kb];
      #pragma unroll
      for (int tc = 0; tc < 8; tc++) {
        acc[0][tc] = __builtin_amdgcn_mfma_f32_16x16x32_bf16(af0, bf[tc], acc[0][tc], 0, 0, 0);
        acc[1][tc] = __builtin_amdgcn_mfma_f32_16x16x32_bf16(af1, bf[tc], acc[1][tc], 0, 0, 0);
      }
    }
    __syncthreads();
  }
  float sv[8], qv[8], bj[8];
  #pragma unroll
  for (int tc = 0; tc < 8; tc++) {
    bj[tc] = bias[tc*16 + l15];
    sv[tc] = 0.f; qv[tc] = 0.f;
  }
  #pragma unroll
  for (int tr = 0; tr < 2; tr++) {
    int rbase = n0 + w*32 + tr*16 + quad*4;
    #pragma unroll
    for (int tc = 0; tc < 8; tc++) {
      int col = tc*16 + l15;
      #pragma unroll
      for (int g = 0; g < 4; g++) {
        int r = rbase + g;
        if (r < NN) {
          float v = acc[tr][tc][g] + bj[tc];
          float y = v > 0.f ? v : 0.f;
          sv[tc] += y; qv[tc] += y*y;
          A1[(size_t)r*FD + col] = f2bf(v);
        }
      }
    }
  }
  #pragma unroll
  for (int tc = 0; tc < 8; tc++) {
    sv[tc] += __shfl_xor(sv[tc], 16); qv[tc] += __shfl_xor(qv[tc], 16);
    sv[tc] += __shfl_xor(sv[tc], 32); qv[tc] += __shfl_xor(qv[tc], 32);
  }
  if (quad == 0) {
    #pragma unroll
    for (int tc = 0; tc < 8; tc++) {
      Sred[0][w][tc*16 + l15] = sv[tc];
      Sred[1][w][tc*16 + l15] = qv[tc];
    }
  }
  __syncthreads();
  if (tid < 128) {
    float s = Sred[0][0][tid] + Sred[0][1][tid] + Sred[0][2][tid] + Sred[0][3][tid];
    float q = Sred[1][0][tid] + Sred[1][1][tid] + Sred[1][2][tid] + Sred[1][3][tid];
    atomicAdd(&accSQ[ty*128 + tid], s);
    atomicAdd(&accSQ[256 + ty*128 + tid], q);
  }
}

// tiny: fold accumulated stats -> scale/shift; re-zero accumulators for next layer
__global__ __launch_bounds__(256) void k_bnfinal(float* __restrict__ accSQ,
                                                 const float* __restrict__ gu,
                                                 const float* __restrict__ bu,
                                                 const float* __restrict__ gi,
                                                 const float* __restrict__ bi,
                                                 float* __restrict__ bnsc,
                                                 float* __restrict__ bnsh) {
  int tid = threadIdx.x;
  int type = tid >> 7;            // 0=user, 1=item
  int c = tid & 127;
  float s = accSQ[tid];
  float q = accSQ[256 + tid];
  accSQ[tid] = 0.f;
  accSQ[256 + tid] = 0.f;
  float inv = 1.0f / (float)NN;
  float mean = s * inv;
  float var = q * inv - mean*mean;
  float rstd = rsqrtf(var + BNEPS);
  float g = type ? gi[c] : gu[c];
  float bb = type ? bi[c] : bu[c];
  float sc = rstd * g;
  bnsc[tid] = sc;
  bnsh[tid] = bb - mean * sc;
}

// BN-apply + mean-pool, one block per graph (both node types); rows of each
// type are contiguous (batch ids sorted). int4 (8 bf16) vectorized, no atomics.
__global__ __launch_bounds__(256) void k_bnpool(const u16* __restrict__ newU,
                                                const u16* __restrict__ newI,
                                                const int* __restrict__ ustart,
                                                const int* __restrict__ istart,
                                                const float* __restrict__ bnsc,
                                                const float* __restrict__ bnsh,
                                                const float* __restrict__ invcnt,
                                                u16* __restrict__ xu,
                                                u16* __restrict__ xi,
                                                float* __restrict__ feats) {
  __shared__ float red[16][128];
  int tid = threadIdx.x;
  int g = blockIdx.x;
  int rt = tid >> 4;        // 0..15 row thread
  int c8 = (tid & 15) * 8;  // col group base
  float acc[8];
  #pragma unroll
  for (int j = 0; j < 8; j++) acc[j] = 0.f;
  #pragma unroll
  for (int type = 0; type < 2; type++) {
    const u16* in = type ? newI : newU;
    u16* out = type ? xi : xu;
    const int* st = type ? istart : ustart;
    int rs = st[g], re = st[g+1];
    float sc[8], sh[8];
    #pragma unroll
    for (int j = 0; j < 8; j++) {
      sc[j] = bnsc[type*128 + c8 + j];
      sh[j] = bnsh[type*128 + c8 + j];
    }
    int r = rs + rt;
    // 2-deep row pipeline for MLP
    for (; r + 16 < re; r += 32) {
      int4 v0 = *(const int4*)(in + (size_t)r*FD + c8);
      int4 v1 = *(const int4*)(in + (size_t)(r+16)*FD + c8);
      float f0[8], f1[8];
      unp8(f0, v0); unp8(f1, v1);
      u16 ov[8];
      #pragma unroll
      for (int j = 0; j < 8; j++) {
        float y = f0[j] > 0.f ? f0[j] : 0.f;
        float o = y * sc[j] + sh[j];
        ov[j] = f2bf(o); acc[j] += o;
      }
      int4 ow;
      ow.x = (unsigned)ov[0] | ((unsigned)ov[1] << 16);
      ow.y = (unsigned)ov[2] | ((unsigned)ov[3] << 16);
      ow.z = (unsigned)ov[4] | ((unsigned)ov[5] << 16);
      ow.w = (unsigned)ov[6] | ((unsigned)ov[7] << 16);
      *(int4*)(out + (size_t)r*FD + c8) = ow;
      #pragma unroll
      for (int j = 0; j < 8; j++) {
        float y = f1[j] > 0.f ? f1[j] : 0.f;
        float o = y * sc[j] + sh[j];
        ov[j] = f2bf(o); acc[j] += o;
      }
      ow.x = (unsigned)ov[0] | ((unsigned)ov[1] << 16);
      ow.y = (unsigned)ov[2] | ((unsigned)ov[3] << 16);
      ow.z = (unsigned)ov[4] | ((unsigned)ov[5] << 16);
      ow.w = (unsigned)ov[6] | ((unsigned)ov[7] << 16);
      *(int4*)(out + (size_t)(r+16)*FD + c8) = ow;
    }
    for (; r < re; r += 16) {
      int4 v0 = *(const int4*)(in + (size_t)r*FD + c8);
      float f0[8];
      unp8(f0, v0);
      u16 ov[8];
      #pragma unroll
      for (int j = 0; j < 8; j++) {
        float y = f0[j] > 0.f ? f0[j] : 0.f;
        float o = y * sc[j] + sh[j];
        ov[j] = f2bf(o); acc[j] += o;
      }
      int4 ow;
      ow.x = (unsigned)ov[0] | ((unsigned)ov[1] << 16);
      ow.y = (unsigned)ov[2] | ((unsigned)ov[3] << 16);
      ow.z = (unsigned)ov[4] | ((unsigned)ov[5] << 16);
      ow.w = (unsigned)ov[6] | ((unsigned)ov[7] << 16);
      *(int4*)(out + (size_t)r*FD + c8) = ow;
    }
  }
  #pragma unroll
  for (int j = 0; j < 8; j++) red[rt][c8 + j] = acc[j];
  __syncthreads();
  if (tid < 128) {
    float s = 0.f;
    #pragma unroll
    for (int i = 0; i < 16; i++) s += red[i][tid];
    feats[(size_t)g*FD + tid] = s * invcnt[g];
  }
}

__global__ __launch_bounds__(256) void k_heads(const float* __restrict__ feats,
                                               const float* __restrict__ fcW,
                                               const float* __restrict__ fcb,
                                               float* __restrict__ logits) {
  int idx = blockIdx.x*256 + threadIdx.x;
  if (idx >= LOGITS_N) return;
  int l = idx >> 13;
  int rem = idx & 8191;
  int g = rem >> 4;
  int c = rem & 15;
  const float* f = feats + ((size_t)l*NG + g)*FD;
  const float* w = fcW + ((size_t)l*NC + c)*FD;
  float s = 0.f;
  #pragma unroll
  for (int k = 0; k < FD; k += 4) {
    float4 fv = *(const float4*)(f + k);
    float4 wv = *(const float4*)(w + k);
    s += fv.x*wv.x + fv.y*wv.y + fv.z*wv.z + fv.w*wv.w;
  }
  logits[idx] = s + fcb[l*NC + c];
}

extern "C" void kernel_launch(void* const* d_in, const int* in_sizes, int n_in,
                              void* d_out, int out_size, void* d_ws, size_t ws_size,
                              hipStream_t stream) {
  const float* x_user   = (const float*)d_in[0];
  const float* x_item   = (const float*)d_in[1];
  const int*   eu2i     = (const int*)d_in[2];
  const int*   ei2u     = (const int*)d_in[3];
  const int*   bu       = (const int*)d_in[4];
  const int*   bi       = (const int*)d_in[5];
  const float* Wrel_u2i = (const float*)d_in[6];
  const float* Wroot_u2i= (const float*)d_in[7];
  const float* b_u2i    = (const float*)d_in[8];
  const float* Wrel_i2u = (const float*)d_in[9];
  const float* Wroot_i2u= (const float*)d_in[10];
  const float* b_i2u    = (const float*)d_in[11];
  const float* bn_g_user= (const float*)d_in[12];
  const float* bn_b_user= (const float*)d_in[13];
  const float* bn_g_item= (const float*)d_in[14];
  const float* bn_b_item= (const float*)d_in[15];
  const float* fcW      = (const float*)d_in[16];
  const float* fcb      = (const float*)d_in[17];

  char* ws = (char*)d_ws;
  int*   gcnt   = (int*)(ws + OFF_GCNT);
  int*   bcursor= (int*)(ws + OFF_BCUR);
  float* accSQ  = (float*)(ws + OFF_ACC);
  int*   ustart = (int*)(ws + OFF_USTART);
  int*   istart = (int*)(ws + OFF_ISTART);
  float* invcnt = (float*)(ws + OFF_INVCNT);
  float* bnsc   = (float*)(ws + OFF_BNSC);
  float* bnsh   = (float*)(ws + OFF_BNSH);
  int2*  rowrange = (int2*)(ws + OFF_ROWRANGE);
  u16*   WB     = (u16*)(ws + OFF_WB);
  int*   csrbin = (int*)(ws + OFF_CSR);
  u16*   aggI   = (u16*)(ws + OFF_AGGI);
  u16*   aggU   = (u16*)(ws + OFF_AGGU);
  u16*   xu     = (u16*)(ws + OFF_XU);
  u16*   xi     = (u16*)(ws + OFF_XI);
  u16*   xu0    = (u16*)(ws + OFF_XU0);
  u16*   xi0    = (u16*)(ws + OFF_XI0);
  float* fout   = (float*)d_out;
  float* featsAll = fout + LOGITS_N;

  hipMemsetAsync(ws, 0, MEMSET_BYTES, stream);
  k_hist_batch<<<NBLK, 256, 0, stream>>>(bu, bi, gcnt);
  k_bin<<<NBINBLK, 256, 0, stream>>>(eu2i, ei2u, bcursor, csrbin);
  k_scan_g<<<1, 512, 0, stream>>>(gcnt, ustart, istart, invcnt);
  k_csrbuild<<<NBUCK, 256, 0, stream>>>(bcursor, csrbin, rowrange);
  k_castX<<<12500, 256, 0, stream>>>(x_user, x_item, xu0, xi0);
  k_castW<<<768, 256, 0, stream>>>(Wrel_u2i, Wroot_u2i, Wrel_i2u, Wroot_i2u, WB);

  const u16* curU = xu0;
  const u16* curI = xi0;
  for (int l = 0; l < NL; l++) {
    k_gather<<<25000, 256, 0, stream>>>(curU, curI, rowrange, csrbin, aggI, aggU);
    k_gemm<<<dim3(NBLK,2), 256, 0, stream>>>(aggU, aggI, curU, curI,
                                             WB + (size_t)l*2*32768,
                                             b_i2u + l*FD, b_u2i + l*FD,
                                             accSQ);
    k_bnfinal<<<1, 256, 0, stream>>>(accSQ, bn_g_user, bn_b_user,
                                     bn_g_item, bn_b_item, bnsc, bnsh);
    k_bnpool<<<NG, 256, 0, stream>>>(aggU, aggI, ustart, istart, bnsc, bnsh,
                                     invcnt, xu, xi,
                                     featsAll + (size_t)l*NG*FD);
    curU = xu; curI = xi;
  }
  k_heads<<<96, 256, 0, stream>>>(featsAll, fcW, fcb, fout);
}